// Round 8
// baseline (188.790 us; speedup 1.0000x reference)
//
#include <hip/hip_runtime.h>
#include <hip/hip_bf16.h>

// MyMSA: B=4 S=2048 D=1024 H=16 DH=64. fp32 in/out. bf16 MFMA, fp32 accum.
//
// R15 = R13 (32x32x16, sigma K-perm, tree-sum lacc, 256thr/4-wave blocks,
// grid 1024, KT=64, conflicts=0) + T15 two-deep score pipeline:
// keep sP/sN (two f32x16 score tiles) live; per 32-key group j the wave
// issues QK MFMAs for group j+1, THEN the finish (exp2+cvt+PV) of group j
// -> independent in-wave ILP fills the QK->exp2->PV dependency latency
// that caused the ~24% dead time (MfmaUtil+VALU = 76% across 7 variants
// stuck at 77-86us). m214 v36 measured +7-11% for exactly this.
// V-frags for the deferred finish are captured in registers pre-barrier,
// so the single barrier/tile and double-buffer invariants are unchanged.
// setprio dropped (R14/m190: null in lockstep; constrains interleave).
// Standing lessons: no direct-from-global operand frags (R8/R9); spill
// cliff ~190 live regs (R12) - peak here ~150; 8-wave blocks hurt (R14);
// occupancy not a lever (R14); barrier count not a lever (R11).

typedef unsigned short u16;
typedef unsigned int   u32;
typedef float  f32x4   __attribute__((ext_vector_type(4)));
typedef float  f32x16  __attribute__((ext_vector_type(16)));
typedef __bf16 bf16x4  __attribute__((ext_vector_type(4)));
typedef __bf16 bf16x8  __attribute__((ext_vector_type(8)));

#define NB 4
#define SS 2048
#define DDIM 1024
#define NH 16
#define DH 64

static __device__ __forceinline__ float fexp2(float x) {
#if __has_builtin(__builtin_amdgcn_exp2f)
    return __builtin_amdgcn_exp2f(x);
#else
    return exp2f(x);
#endif
}
static __device__ __forceinline__ bf16x4 cvt4(f32x4 v) {
    return __builtin_convertvector(v, bf16x4);   // v_cvt_pk_bf16_f32 on gfx950
}
static __device__ __forceinline__ bf16x8 cvt8(f32x4 lo, f32x4 hi) {
    return __builtin_shufflevector(cvt4(lo), cvt4(hi), 0, 1, 2, 3, 4, 5, 6, 7);
}

// ---------------- Kernel 1: QKV projection (R12 verbatim) ----------------
// grid: 64 * 8 = 512 blocks (bh = bid&63 -> co-XCD with attn), 256 threads.
#define WST 72   // W_lds row stride (u16): 144B

__global__ __launch_bounds__(256) void qkv_kernel(
        const float* __restrict__ x,
        const float* __restrict__ Wq, const float* __restrict__ bq,
        const float* __restrict__ Wk, const float* __restrict__ bk,
        const float* __restrict__ Wv, const float* __restrict__ bv,
        u16* __restrict__ Qw, u16* __restrict__ Kw, u16* __restrict__ Vt) {
    __shared__ __align__(16) u16 W_lds[3 * DH * WST];   // 27.6 KB

    const int tid  = threadIdx.x;
    const int w    = tid >> 6;
    const int lane = tid & 63;
    const int quad = lane >> 4;
    const int c    = lane & 15;
    const int bid  = blockIdx.x;
    const int bh   = bid & 63;
    const int s0   = (bid >> 6) * 256;
    const int b    = bh >> 4, h = bh & 15;

    // stage W fp32 -> bf16 into LDS
    {
        const float* Wsrc[3] = {Wq + h*DH*DH, Wk + h*DH*DH, Wv + h*DH*DH};
        #pragma unroll
        for (int j = 0; j < 6; ++j) {
            const int m = j >> 1;
            const int chunk = ((j & 1) << 8) + tid;      // 0..511 within mat
            const float* src = Wsrc[m] + chunk * 8;
            f32x4 lo = *(const f32x4*)src;
            f32x4 hi = *(const f32x4*)(src + 4);
            const int row = chunk >> 3, c8 = chunk & 7;
            *(bf16x8*)&W_lds[(m*DH + row) * WST + c8*8] = cvt8(lo, hi);
        }
    }
    __syncthreads();

    // per-wave W fragments, read from LDS ONCE, reused over 4 token groups
    bf16x8 wf[3][4][2];
    #pragma unroll
    for (int m = 0; m < 3; ++m)
        #pragma unroll
        for (int mt = 0; mt < 4; ++mt)
            #pragma unroll
            for (int kh = 0; kh < 2; ++kh)
                wf[m][mt][kh] = *(const bf16x8*)&W_lds[(m*DH + mt*16 + c) * WST + kh*32 + quad*8];

    f32x4 biasQK[2][4];
    float biasV[4];
    #pragma unroll
    for (int mt = 0; mt < 4; ++mt) {
        biasQK[0][mt] = *(const f32x4*)(bq + h*DH + mt*16 + quad*4);
        biasQK[1][mt] = *(const f32x4*)(bk + h*DH + mt*16 + quad*4);
        biasV[mt] = bv[h*DH + mt*16 + c];
    }

    const size_t qkbase = (size_t)bh * SS * DH;
    const size_t vtbase = (size_t)bh * DH * SS;

    #pragma unroll 1
    for (int g = 0; g < 4; ++g) {
        const int sb = s0 + w*64 + g*16;      // group tokens: sb + c
        const float* xr = x + ((size_t)(b * SS + sb + c)) * DDIM + h * DH;
        bf16x8 xb[2];
        #pragma unroll
        for (int kh = 0; kh < 2; ++kh) {
            f32x4 lo = *(const f32x4*)(xr + kh*32 + quad*8);
            f32x4 hi = *(const f32x4*)(xr + kh*32 + quad*8 + 4);
            xb[kh] = cvt8(lo, hi);
        }

        const int srow = sb + c;
        // sigma: token t -> K-matrix row within its 32-group, chosen so the
        // attn 32x32 S^T C-regs convert straight into PV B-frags.
        const int tq = srow & 31;
        const int sK = (srow & ~31) | (tq & 3)
                     | (((tq >> 3) & 1) << 2)
                     | (((tq >> 2) & 1) << 3)
                     | (((tq >> 4) & 1) << 4);

        // Q, K: swapped operands (A = W frag, B = X^T frag)
        #pragma unroll
        for (int m = 0; m < 2; ++m) {
            const float scale = (m == 0) ? 0.18033688f : 1.0f;  // 0.125*log2(e)
            u16* base = (m == 0 ? Qw : Kw) + qkbase + (size_t)(m == 0 ? srow : sK) * DH;
            #pragma unroll
            for (int mt = 0; mt < 4; ++mt) {
                f32x4 acc = {0.f, 0.f, 0.f, 0.f};
                acc = __builtin_amdgcn_mfma_f32_16x16x32_bf16(wf[m][mt][0], xb[0], acc, 0, 0, 0);
                acc = __builtin_amdgcn_mfma_f32_16x16x32_bf16(wf[m][mt][1], xb[1], acc, 0, 0, 0);
                f32x4 v = (acc + biasQK[m][mt]) * scale;
                *(bf16x4*)(base + mt*16 + quad*4) = cvt4(v);     // b64 store
            }
        }
        // V: non-swapped (A = X frag, B = W frag) -> C rows = tokens
        #pragma unroll
        for (int nt = 0; nt < 4; ++nt) {
            f32x4 acc = {0.f, 0.f, 0.f, 0.f};
            acc = __builtin_amdgcn_mfma_f32_16x16x32_bf16(xb[0], wf[2][nt][0], acc, 0, 0, 0);
            acc = __builtin_amdgcn_mfma_f32_16x16x32_bf16(xb[1], wf[2][nt][1], acc, 0, 0, 0);
            f32x4 v = acc + biasV[nt];
            u16* dst = Vt + vtbase + (size_t)(nt*16 + c) * SS + sb + quad*4;
            *(bf16x4*)dst = cvt4(v);                             // b64 along s
        }
    }
}

// ---------------- Kernel 2: flash attention, 32x32x16, T15 pipeline -----
// grid: 64 * 16 = 1024 blocks, 256 threads (4 waves x 32 q rows).
#define KT 64
#define KST 72    // K_lds row stride (u16): 144B
#define VST 72    // V_lds row stride (u16): 144B

#define Z16 {0.f,0.f,0.f,0.f,0.f,0.f,0.f,0.f,0.f,0.f,0.f,0.f,0.f,0.f,0.f,0.f}

// QK MFMAs for group g of LDS tile Kp -> score tile sdst
#define QKG(Kp, g, sdst) do {                                                  \
        bf16x8 ka0 = *(const bf16x8*)&Kp[((g)*32 + l31) * KST +  0 + hi*8];    \
        bf16x8 ka1 = *(const bf16x8*)&Kp[((g)*32 + l31) * KST + 16 + hi*8];    \
        bf16x8 ka2 = *(const bf16x8*)&Kp[((g)*32 + l31) * KST + 32 + hi*8];    \
        bf16x8 ka3 = *(const bf16x8*)&Kp[((g)*32 + l31) * KST + 48 + hi*8];    \
        sdst = (f32x16)Z16;                                                    \
        sdst = __builtin_amdgcn_mfma_f32_32x32x16_bf16(ka0, qf[0], sdst, 0,0,0); \
        sdst = __builtin_amdgcn_mfma_f32_32x32x16_bf16(ka1, qf[1], sdst, 0,0,0); \
        sdst = __builtin_amdgcn_mfma_f32_32x32x16_bf16(ka2, qf[2], sdst, 0,0,0); \
        sdst = __builtin_amdgcn_mfma_f32_32x32x16_bf16(ka3, qf[3], sdst, 0,0,0); \
    } while (0)

// capture V frags for group g of LDS tile Vp into registers
#define VFR(Vp, g, vf) do {                                                    \
        vf[0] = *(const bf16x8*)&Vp[( 0 + l31) * VST + (g)*32 +  0 + hi*8];    \
        vf[1] = *(const bf16x8*)&Vp[( 0 + l31) * VST + (g)*32 + 16 + hi*8];    \
        vf[2] = *(const bf16x8*)&Vp[(32 + l31) * VST + (g)*32 +  0 + hi*8];    \
        vf[3] = *(const bf16x8*)&Vp[(32 + l31) * VST + (g)*32 + 16 + hi*8];    \
    } while (0)

// finish a score tile: exp2 in place, l partial, cvt, PV MFMAs (regs only)
#define FIN(s, vf) do {                                                        \
        _Pragma("unroll")                                                      \
        for (int r = 0; r < 16; ++r) s[r] = fexp2(s[r]);                       \
        lp += (((s[0]+s[1])+(s[2]+s[3])) + ((s[4]+s[5])+(s[6]+s[7])))          \
            + (((s[8]+s[9])+(s[10]+s[11])) + ((s[12]+s[13])+(s[14]+s[15])));   \
        bf16x8 pf0 = cvt8((f32x4){s[0],s[1],s[2],s[3]},                        \
                          (f32x4){s[4],s[5],s[6],s[7]});                       \
        bf16x8 pf1 = cvt8((f32x4){s[8],s[9],s[10],s[11]},                      \
                          (f32x4){s[12],s[13],s[14],s[15]});                   \
        o0 = __builtin_amdgcn_mfma_f32_32x32x16_bf16(vf[0], pf0, o0, 0,0,0);   \
        o0 = __builtin_amdgcn_mfma_f32_32x32x16_bf16(vf[1], pf1, o0, 0,0,0);   \
        o1 = __builtin_amdgcn_mfma_f32_32x32x16_bf16(vf[2], pf0, o1, 0,0,0);   \
        o1 = __builtin_amdgcn_mfma_f32_32x32x16_bf16(vf[3], pf1, o1, 0,0,0);   \
    } while (0)

__global__ __launch_bounds__(256, 2) void attn_kernel(
        const u16* __restrict__ Qw, const u16* __restrict__ Kw,
        const u16* __restrict__ Vt, float* __restrict__ out) {
    __shared__ __align__(16) u16 K_lds[2][KT * KST];   // 2 x 9.2 KB
    __shared__ __align__(16) u16 V_lds[2][DH * VST];   // 2 x 9.2 KB

    const int tid  = threadIdx.x;
    const int w    = tid >> 6;
    const int lane = tid & 63;
    const int l31  = lane & 31;
    const int hi   = lane >> 5;
    const int bid  = blockIdx.x;
    const int bh   = bid & 63;           // XCD swizzle: same bh -> same XCD
    const int q0   = (bid >> 6) * 128;
    const int qw   = q0 + w * 32;        // wave's 32 q-rows

    const u16* Qb = Qw + (size_t)bh * SS * DH;
    const u16* Kb = Kw + (size_t)bh * SS * DH;
    const u16* Vb = Vt + (size_t)bh * DH * SS;

    // Q B-frags: col q = l31, k(d) = m*16 + hi*8 + j
    bf16x8 qf[4];
    {
        const u16* qrow = Qb + (size_t)(qw + l31) * DH;
        #pragma unroll
        for (int m = 0; m < 4; ++m)
            qf[m] = *(const bf16x8*)(qrow + m*16 + hi*8);
    }

    f32x16 o0 = Z16, o1 = Z16;   // O^T C-frags (col=q, rows=d 0-31 / 32-63)
    float lp = 0.f;

    // staging: row = tid>>2 (0..63), 16 u16 cols per thread (2x uint4)
    const int strow = tid >> 2;
    const int stcol = (tid & 3) * 16;
    const int kofs  = strow * KST + stcol;
    const int vofs  = strow * VST + stcol;

    uint4 kr0 = *(const uint4*)(Kb + (size_t)strow * DH + stcol);
    uint4 kr1 = *(const uint4*)(Kb + (size_t)strow * DH + stcol + 8);
    uint4 vr0 = *(const uint4*)(Vb + (size_t)strow * SS + stcol);
    uint4 vr1 = *(const uint4*)(Vb + (size_t)strow * SS + stcol + 8);

    // ---- prologue: stage tile 0, prefetch tile 1, QK(g0 of tile 0)
    *(uint4*)&K_lds[0][kofs]     = kr0;
    *(uint4*)&K_lds[0][kofs + 8] = kr1;
    *(uint4*)&V_lds[0][vofs]     = vr0;
    *(uint4*)&V_lds[0][vofs + 8] = vr1;
    __syncthreads();
    kr0 = *(const uint4*)(Kb + (size_t)(KT + strow) * DH + stcol);
    kr1 = *(const uint4*)(Kb + (size_t)(KT + strow) * DH + stcol + 8);
    vr0 = *(const uint4*)(Vb + (size_t)strow * SS + KT + stcol);
    vr1 = *(const uint4*)(Vb + (size_t)strow * SS + KT + stcol + 8);

    f32x16 sP, sN;
    bf16x8 vfP[4], vfN[4];
    QKG(K_lds[0], 0, sP);
    VFR(V_lds[0], 0, vfP);

    // ---- main loop: 31 iterations; at entry sP = scores(g0, tile t)
    #pragma unroll 1
    for (int t = 0; t < 31; ++t) {
        const int cb = t & 1;
        u16* Klc = K_lds[cb];
        u16* Vlc = V_lds[cb];
        u16* Kln = K_lds[cb ^ 1];
        u16* Vln = V_lds[cb ^ 1];

        // QK for group (t, g1), then finish group (t, g0) — independent ops
        QKG(Klc, 1, sN);
        VFR(Vlc, 1, vfN);
        FIN(sP, vfP);

        // stage tile t+1 into the other buffer; barrier; prefetch tile t+2
        *(uint4*)&Kln[kofs]     = kr0;
        *(uint4*)&Kln[kofs + 8] = kr1;
        *(uint4*)&Vln[vofs]     = vr0;
        *(uint4*)&Vln[vofs + 8] = vr1;
        __syncthreads();
        int tn = (t + 2) * KT; if (tn >= SS) tn = 0;   // wrap: dead load
        kr0 = *(const uint4*)(Kb + (size_t)(tn + strow) * DH + stcol);
        kr1 = *(const uint4*)(Kb + (size_t)(tn + strow) * DH + stcol + 8);
        vr0 = *(const uint4*)(Vb + (size_t)strow * SS + tn + stcol);
        vr1 = *(const uint4*)(Vb + (size_t)strow * SS + tn + stcol + 8);

        // QK for group (t+1, g0), then finish group (t, g1)
        QKG(Kln, 0, sP);
        VFR(Vln, 0, vfP);
        FIN(sN, vfN);
    }

    // ---- epilogue: tile 31 (buffer 1): QK(g1), finish both pending groups
    {
        u16* Klc = K_lds[1];
        u16* Vlc = V_lds[1];
        QKG(Klc, 1, sN);
        VFR(Vlc, 1, vfN);
        FIN(sP, vfP);
        FIN(sN, vfN);
    }

    // epilogue: lane holds q = qw + l31; d = dt*32 + 8*rq + 4*hi + (0..3).
    const int b = bh >> 4, h = bh & 15;
    const float lw = lp + __shfl_xor(lp, 32, 64);
    const float inv = 1.0f / lw;
    const int token = qw + l31;
    float* orow = out + ((size_t)b * SS + token) * DDIM + h * DH;
    #pragma unroll
    for (int rq = 0; rq < 4; ++rq) {
        f32x4 v0 = {o0[4*rq+0], o0[4*rq+1], o0[4*rq+2], o0[4*rq+3]};
        f32x4 v1 = {o1[4*rq+0], o1[4*rq+1], o1[4*rq+2], o1[4*rq+3]};
        v0 = v0 * inv;
        v1 = v1 * inv;
        *(f32x4*)(orow +      8*rq + 4*hi) = v0;
        *(f32x4*)(orow + 32 + 8*rq + 4*hi) = v1;
    }
}

extern "C" void kernel_launch(void* const* d_in, const int* in_sizes, int n_in,
                              void* d_out, int out_size, void* d_ws, size_t ws_size,
                              hipStream_t stream) {
    const float* x  = (const float*)d_in[0];
    const float* Wq = (const float*)d_in[1];
    const float* bq = (const float*)d_in[2];
    const float* Wk = (const float*)d_in[3];
    const float* bk = (const float*)d_in[4];
    const float* Wv = (const float*)d_in[5];
    const float* bv = (const float*)d_in[6];

    // ws: Qw[bh][s][d], Kw[bh][s'][d] (s sigma-permuted per 32), Vt[bh][d][s]
    u16* Qw = (u16*)d_ws;
    u16* Kw = Qw + (size_t)NB * NH * SS * DH;
    u16* Vt = Kw + (size_t)NB * NH * SS * DH;

    qkv_kernel<<<64 * (SS / 256), 256, 0, stream>>>(
        x, Wq, bq, Wk, bk, Wv, bv, Qw, Kw, Vt);
    attn_kernel<<<64 * (SS / 128), 256, 0, stream>>>(Qw, Kw, Vt, (float*)d_out);
}

// Round 10
// 169.693 us; speedup vs baseline: 1.1125x; 1.1125x over previous
//
#include <hip/hip_runtime.h>
#include <hip/hip_bf16.h>

// MyMSA: B=4 S=2048 D=1024 H=16 DH=64. fp32 in/out. bf16 MFMA, fp32 accum.
//
// R17 = R16 resubmitted (Round 9 failed on container acquisition, not the
// kernel: "MI355X container failed twice" precedes compile/test).
// attn reverted to R11 verbatim (best measured 76.7us; 8 structural
// attn variants all 77-86us -> in-structure attn exhausted). The lever is
// qkv, unprofiled since R6: total - attn = 102-107us CONSTANT across all
// rounds, and the R6 qkv is latency-serialized (512 blocks = 2/CU, serial
// 4-iter g-loop, each exposing full HBM latency on its x-loads, ~96 VGPR
// of W frags held live). qkv v2, same verified math:
//  * grid 1024 (128 tok/block) -> 4 blocks/CU, 16 waves/CU.
//  * 2 groups/wave, ALL 8 x-loads issued up-front (one latency exposure).
//  * W frags read from LDS at use (once per 2 groups) - no 96-reg cache.
// Floor 82MB HBM ~14us; predict 18-25us. If total only returns to ~175,
// qkv was fast and the ~100us residue is fixed overhead -> declare.
// Standing lessons: no direct-from-global operand frags (R8/R9); spill
// cliff ~190 live (R12); occupancy/barrier-count/LDS-placement/T15 not
// levers for attn (R10/R11/R14/R15).

typedef unsigned short u16;
typedef unsigned int   u32;
typedef float  f32x4  __attribute__((ext_vector_type(4)));
typedef __bf16 bf16x4 __attribute__((ext_vector_type(4)));
typedef __bf16 bf16x8 __attribute__((ext_vector_type(8)));

#define NB 4
#define SS 2048
#define DDIM 1024
#define NH 16
#define DH 64

static __device__ __forceinline__ float fexp2(float x) {
#if __has_builtin(__builtin_amdgcn_exp2f)
    return __builtin_amdgcn_exp2f(x);
#else
    return exp2f(x);
#endif
}
static __device__ __forceinline__ bf16x4 cvt4(f32x4 v) {
    return __builtin_convertvector(v, bf16x4);   // v_cvt_pk_bf16_f32 on gfx950
}
static __device__ __forceinline__ bf16x8 cvt8(f32x4 lo, f32x4 hi) {
    return __builtin_shufflevector(cvt4(lo), cvt4(hi), 0, 1, 2, 3, 4, 5, 6, 7);
}

// ---------------- Kernel 1: QKV projection v2 ----------------
// grid: 64 * 16 = 1024 blocks (bh = bid&63 -> co-XCD with attn), 256 thr.
// Each wave: 32 tokens (2 groups of 16), all x-loads up front, W from LDS.
#define WST 72   // W_lds row stride (u16): 144B

__global__ __launch_bounds__(256) void qkv_kernel(
        const float* __restrict__ x,
        const float* __restrict__ Wq, const float* __restrict__ bq,
        const float* __restrict__ Wk, const float* __restrict__ bk,
        const float* __restrict__ Wv, const float* __restrict__ bv,
        u16* __restrict__ Qw, u16* __restrict__ Kw, u16* __restrict__ Vt) {
    __shared__ __align__(16) u16 W_lds[3 * DH * WST];   // 27.6 KB

    const int tid  = threadIdx.x;
    const int w    = tid >> 6;
    const int lane = tid & 63;
    const int quad = lane >> 4;
    const int c    = lane & 15;
    const int bid  = blockIdx.x;
    const int bh   = bid & 63;
    const int s0   = (bid >> 6) * 128;
    const int b    = bh >> 4, h = bh & 15;

    // stage W fp32 -> bf16 into LDS (W total 786KB -> L2-resident re-reads)
    {
        const float* Wsrc[3] = {Wq + h*DH*DH, Wk + h*DH*DH, Wv + h*DH*DH};
        #pragma unroll
        for (int j = 0; j < 6; ++j) {
            const int m = j >> 1;
            const int chunk = ((j & 1) << 8) + tid;      // 0..511 within mat
            const float* src = Wsrc[m] + chunk * 8;
            f32x4 lo = *(const f32x4*)src;
            f32x4 hi = *(const f32x4*)(src + 4);
            const int row = chunk >> 3, c8 = chunk & 7;
            *(bf16x8*)&W_lds[(m*DH + row) * WST + c8*8] = cvt8(lo, hi);
        }
    }

    // x loads for BOTH groups issued before the barrier: 8 independent
    // dwordx4 in flight -> one latency exposure for the whole block.
    const int sbA = s0 + w*32;          // group A tokens: sbA + c
    const int sbB = sbA + 16;           // group B tokens: sbB + c
    const float* xrA = x + ((size_t)(b * SS + sbA + c)) * DDIM + h * DH;
    const float* xrB = x + ((size_t)(b * SS + sbB + c)) * DDIM + h * DH;
    f32x4 a0 = *(const f32x4*)(xrA + quad*8);
    f32x4 a1 = *(const f32x4*)(xrA + quad*8 + 4);
    f32x4 a2 = *(const f32x4*)(xrA + 32 + quad*8);
    f32x4 a3 = *(const f32x4*)(xrA + 32 + quad*8 + 4);
    f32x4 b0 = *(const f32x4*)(xrB + quad*8);
    f32x4 b1 = *(const f32x4*)(xrB + quad*8 + 4);
    f32x4 b2 = *(const f32x4*)(xrB + 32 + quad*8);
    f32x4 b3 = *(const f32x4*)(xrB + 32 + quad*8 + 4);

    f32x4 biasQK[2][4];
    float biasV[4];
    #pragma unroll
    for (int mt = 0; mt < 4; ++mt) {
        biasQK[0][mt] = *(const f32x4*)(bq + h*DH + mt*16 + quad*4);
        biasQK[1][mt] = *(const f32x4*)(bk + h*DH + mt*16 + quad*4);
        biasV[mt] = bv[h*DH + mt*16 + c];
    }

    __syncthreads();

    bf16x8 xbA[2] = { cvt8(a0, a1), cvt8(a2, a3) };
    bf16x8 xbB[2] = { cvt8(b0, b1), cvt8(b2, b3) };

    const size_t qkbase = (size_t)bh * SS * DH;
    const size_t vtbase = (size_t)bh * DH * SS;

    // K-row permutation (R6/R11 16-wide form)
    const int srowA = sbA + c, srowB = sbB + c;
    const int tqA = srowA & 31, tqB = srowB & 31;
    const int sKA = (srowA & ~31) | ((tqA & 4) << 2) | ((tqA >> 3) << 2) | (tqA & 3);
    const int sKB = (srowB & ~31) | ((tqB & 4) << 2) | ((tqB >> 3) << 2) | (tqB & 3);

    // Q, K: swapped operands (A = W frag from LDS, B = X^T frag)
    #pragma unroll
    for (int m = 0; m < 2; ++m) {
        const float scale = (m == 0) ? 0.18033688f : 1.0f;  // 0.125*log2(e)
        u16* baseA = (m == 0 ? Qw : Kw) + qkbase + (size_t)(m == 0 ? srowA : sKA) * DH;
        u16* baseB = (m == 0 ? Qw : Kw) + qkbase + (size_t)(m == 0 ? srowB : sKB) * DH;
        #pragma unroll
        for (int mt = 0; mt < 4; ++mt) {
            const bf16x8 w0 = *(const bf16x8*)&W_lds[(m*DH + mt*16 + c) * WST + quad*8];
            const bf16x8 w1 = *(const bf16x8*)&W_lds[(m*DH + mt*16 + c) * WST + 32 + quad*8];
            f32x4 accA = {0.f, 0.f, 0.f, 0.f};
            accA = __builtin_amdgcn_mfma_f32_16x16x32_bf16(w0, xbA[0], accA, 0, 0, 0);
            accA = __builtin_amdgcn_mfma_f32_16x16x32_bf16(w1, xbA[1], accA, 0, 0, 0);
            f32x4 accB = {0.f, 0.f, 0.f, 0.f};
            accB = __builtin_amdgcn_mfma_f32_16x16x32_bf16(w0, xbB[0], accB, 0, 0, 0);
            accB = __builtin_amdgcn_mfma_f32_16x16x32_bf16(w1, xbB[1], accB, 0, 0, 0);
            f32x4 vA = (accA + biasQK[m][mt]) * scale;
            f32x4 vB = (accB + biasQK[m][mt]) * scale;
            *(bf16x4*)(baseA + mt*16 + quad*4) = cvt4(vA);   // b64 store
            *(bf16x4*)(baseB + mt*16 + quad*4) = cvt4(vB);
        }
    }
    // V: non-swapped (A = X frag, B = W frag) -> C rows = tokens
    #pragma unroll
    for (int nt = 0; nt < 4; ++nt) {
        const bf16x8 w0 = *(const bf16x8*)&W_lds[(2*DH + nt*16 + c) * WST + quad*8];
        const bf16x8 w1 = *(const bf16x8*)&W_lds[(2*DH + nt*16 + c) * WST + 32 + quad*8];
        f32x4 accA = {0.f, 0.f, 0.f, 0.f};
        accA = __builtin_amdgcn_mfma_f32_16x16x32_bf16(xbA[0], w0, accA, 0, 0, 0);
        accA = __builtin_amdgcn_mfma_f32_16x16x32_bf16(xbA[1], w1, accA, 0, 0, 0);
        f32x4 accB = {0.f, 0.f, 0.f, 0.f};
        accB = __builtin_amdgcn_mfma_f32_16x16x32_bf16(xbB[0], w0, accB, 0, 0, 0);
        accB = __builtin_amdgcn_mfma_f32_16x16x32_bf16(xbB[1], w1, accB, 0, 0, 0);
        f32x4 vA = accA + biasV[nt];
        f32x4 vB = accB + biasV[nt];
        u16* dstA = Vt + vtbase + (size_t)(nt*16 + c) * SS + sbA + quad*4;
        u16* dstB = Vt + vtbase + (size_t)(nt*16 + c) * SS + sbB + quad*4;
        *(bf16x4*)dstA = cvt4(vA);                           // b64 along s
        *(bf16x4*)dstB = cvt4(vB);
    }
}

// ---------------- Kernel 2: flash attention (R11 verbatim) ----------------
// grid: 64 * 8 = 512 blocks, 256 threads (4 waves x 64 q = 4 qt). KT=128.
#define KT 128
#define KST 72    // K_lds row stride (u16): 144B
#define VST 136   // V_lds row stride (u16): 272B (128 cols + pad 8)

#define LOAD_FRAGS(kf, vf, g) do {                                             \
        kf[0] = *(const bf16x8*)&Kl[((g)*32 + c) * KST + quad*8];              \
        kf[1] = *(const bf16x8*)&Kl[((g)*32 + c) * KST + 32 + quad*8];         \
        kf[2] = *(const bf16x8*)&Kl[((g)*32 + 16 + c) * KST + quad*8];         \
        kf[3] = *(const bf16x8*)&Kl[((g)*32 + 16 + c) * KST + 32 + quad*8];    \
        vf[0] = *(const bf16x8*)&Vl[( 0 + c) * VST + (g)*32 + quad*8];         \
        vf[1] = *(const bf16x8*)&Vl[(16 + c) * VST + (g)*32 + quad*8];         \
        vf[2] = *(const bf16x8*)&Vl[(32 + c) * VST + (g)*32 + quad*8];         \
        vf[3] = *(const bf16x8*)&Vl[(48 + c) * VST + (g)*32 + quad*8];         \
    } while (0)

#define COMPUTE_G(kf, vf) do {                                                 \
        __builtin_amdgcn_s_setprio(1);                                         \
        _Pragma("unroll")                                                      \
        for (int qt = 0; qt < 4; ++qt) {                                       \
            f32x4 sA = {0.f,0.f,0.f,0.f}, sB = {0.f,0.f,0.f,0.f};              \
            sA = __builtin_amdgcn_mfma_f32_16x16x32_bf16(kf[0], qf[qt][0], sA, 0,0,0); \
            sA = __builtin_amdgcn_mfma_f32_16x16x32_bf16(kf[1], qf[qt][1], sA, 0,0,0); \
            sB = __builtin_amdgcn_mfma_f32_16x16x32_bf16(kf[2], qf[qt][0], sB, 0,0,0); \
            sB = __builtin_amdgcn_mfma_f32_16x16x32_bf16(kf[3], qf[qt][1], sB, 0,0,0); \
            f32x4 eA, eB;                                                      \
            _Pragma("unroll")                                                  \
            for (int r = 0; r < 4; ++r) { eA[r] = fexp2(sA[r]); eB[r] = fexp2(sB[r]); } \
            bf16x8 pf = cvt8(eA, eB);                                          \
            o[0][qt] = __builtin_amdgcn_mfma_f32_16x16x32_bf16(vf[0], pf, o[0][qt], 0,0,0); \
            o[1][qt] = __builtin_amdgcn_mfma_f32_16x16x32_bf16(vf[1], pf, o[1][qt], 0,0,0); \
            o[2][qt] = __builtin_amdgcn_mfma_f32_16x16x32_bf16(vf[2], pf, o[2][qt], 0,0,0); \
            o[3][qt] = __builtin_amdgcn_mfma_f32_16x16x32_bf16(vf[3], pf, o[3][qt], 0,0,0); \
            lacc[qt] = __builtin_amdgcn_mfma_f32_16x16x32_bf16(ones8, pf, lacc[qt], 0,0,0); \
        }                                                                      \
        __builtin_amdgcn_s_setprio(0);                                         \
    } while (0)

__global__ __launch_bounds__(256, 2) void attn_kernel(
        const u16* __restrict__ Qw, const u16* __restrict__ Kw,
        const u16* __restrict__ Vt, float* __restrict__ out) {
    __shared__ __align__(16) u16 K_lds[2][KT * KST];   // 2 x 18.4 KB
    __shared__ __align__(16) u16 V_lds[2][DH * VST];   // 2 x 17.4 KB

    const int tid  = threadIdx.x;
    const int w    = tid >> 6;
    const int lane = tid & 63;
    const int quad = lane >> 4;
    const int c    = lane & 15;
    const int bid  = blockIdx.x;
    const int bh   = bid & 63;           // XCD swizzle: same bh -> same XCD
    const int q0   = (bid >> 6) * 256;
    const int qw   = q0 + w * 64;        // wave's 64 q-rows (4 qt)

    const u16* Qb = Qw + (size_t)bh * SS * DH;
    const u16* Kb = Kw + (size_t)bh * SS * DH;
    const u16* Vb = Vt + (size_t)bh * DH * SS;

    // Q B-frags (n=q=c, k=d=quad*8+j)
    bf16x8 qf[4][2];
    #pragma unroll
    for (int qt = 0; qt < 4; ++qt) {
        const u16* qrow = Qb + (size_t)(qw + qt*16 + c) * DH;
        qf[qt][0] = *(const bf16x8*)(qrow + quad*8);
        qf[qt][1] = *(const bf16x8*)(qrow + 32 + quad*8);
    }

    f32x4 o[4][4];      // o[dt][qt]: O^T C-frags (col=q, row=d-local)
    f32x4 lacc[4];
    #pragma unroll
    for (int qt = 0; qt < 4; ++qt) {
        lacc[qt] = (f32x4){0.f, 0.f, 0.f, 0.f};
        #pragma unroll
        for (int dt = 0; dt < 4; ++dt) o[dt][qt] = (f32x4){0.f, 0.f, 0.f, 0.f};
    }

    bf16x8 ones8;
    { union { u16 u[8]; bf16x8 v; } one;
      #pragma unroll
      for (int i = 0; i < 8; ++i) one.u[i] = 0x3F80;
      ones8 = one.v; }

    // K staging: 128 rows, 2 threads/row, 32 u16 each (4x uint4)
    const int krow = tid >> 1;
    const int kcol = (tid & 1) * 32;
    const int kofs = krow * KST + kcol;
    // V staging: 64 rows, 4 threads/row, 32 u16 each (4x uint4)
    const int vrow = tid >> 2;
    const int vcol = (tid & 3) * 32;
    const int vofs = vrow * VST + vcol;

    uint4 kr0 = *(const uint4*)(Kb + (size_t)krow * DH + kcol);
    uint4 kr1 = *(const uint4*)(Kb + (size_t)krow * DH + kcol + 8);
    uint4 kr2 = *(const uint4*)(Kb + (size_t)krow * DH + kcol + 16);
    uint4 kr3 = *(const uint4*)(Kb + (size_t)krow * DH + kcol + 24);
    uint4 vr0 = *(const uint4*)(Vb + (size_t)vrow * SS + vcol);
    uint4 vr1 = *(const uint4*)(Vb + (size_t)vrow * SS + vcol + 8);
    uint4 vr2 = *(const uint4*)(Vb + (size_t)vrow * SS + vcol + 16);
    uint4 vr3 = *(const uint4*)(Vb + (size_t)vrow * SS + vcol + 24);

    #pragma unroll 1
    for (int t0 = 0; t0 < SS; t0 += KT) {
        const int bsel = (t0 >> 7) & 1;
        u16* Kl = K_lds[bsel];
        u16* Vl = V_lds[bsel];
        // store tile t0 (prefetch vmcnt drains here, after a compute phase)
        *(uint4*)&Kl[kofs]      = kr0;
        *(uint4*)&Kl[kofs + 8]  = kr1;
        *(uint4*)&Kl[kofs + 16] = kr2;
        *(uint4*)&Kl[kofs + 24] = kr3;
        *(uint4*)&Vl[vofs]      = vr0;
        *(uint4*)&Vl[vofs + 8]  = vr1;
        *(uint4*)&Vl[vofs + 16] = vr2;
        *(uint4*)&Vl[vofs + 24] = vr3;
        __syncthreads();                       // single barrier per iter
        int tn = t0 + KT; if (tn >= SS) tn = 0;    // wrap: harmless reload
        kr0 = *(const uint4*)(Kb + (size_t)(tn + krow) * DH + kcol);
        kr1 = *(const uint4*)(Kb + (size_t)(tn + krow) * DH + kcol + 8);
        kr2 = *(const uint4*)(Kb + (size_t)(tn + krow) * DH + kcol + 16);
        kr3 = *(const uint4*)(Kb + (size_t)(tn + krow) * DH + kcol + 24);
        vr0 = *(const uint4*)(Vb + (size_t)vrow * SS + tn + vcol);
        vr1 = *(const uint4*)(Vb + (size_t)vrow * SS + tn + vcol + 8);
        vr2 = *(const uint4*)(Vb + (size_t)vrow * SS + tn + vcol + 16);
        vr3 = *(const uint4*)(Vb + (size_t)vrow * SS + tn + vcol + 24);

        // software-pipelined groups: read g+1 frags before computing g
        bf16x8 kfA[4], vfA[4], kfB[4], vfB[4];
        LOAD_FRAGS(kfA, vfA, 0);
        LOAD_FRAGS(kfB, vfB, 1);
        COMPUTE_G(kfA, vfA);
        LOAD_FRAGS(kfA, vfA, 2);
        COMPUTE_G(kfB, vfB);
        LOAD_FRAGS(kfB, vfB, 3);
        COMPUTE_G(kfA, vfA);
        COMPUTE_G(kfB, vfB);
    }

    // epilogue: lane holds token = qw + qt*16 + c, d = dt*16 + quad*4 + r
    const int b = bh >> 4, h = bh & 15;
    #pragma unroll
    for (int qt = 0; qt < 4; ++qt) {
        const float inv = 1.0f / lacc[qt][0];
        const int token = qw + qt*16 + c;
        float* orow = out + ((size_t)b * SS + token) * DDIM + h * DH;
        #pragma unroll
        for (int dt = 0; dt < 4; ++dt) {
            f32x4 vv = o[dt][qt] * inv;
            *(f32x4*)(orow + dt*16 + quad*4) = vv;
        }
    }
}

extern "C" void kernel_launch(void* const* d_in, const int* in_sizes, int n_in,
                              void* d_out, int out_size, void* d_ws, size_t ws_size,
                              hipStream_t stream) {
    const float* x  = (const float*)d_in[0];
    const float* Wq = (const float*)d_in[1];
    const float* bq = (const float*)d_in[2];
    const float* Wk = (const float*)d_in[3];
    const float* bk = (const float*)d_in[4];
    const float* Wv = (const float*)d_in[5];
    const float* bv = (const float*)d_in[6];

    // ws: Qw[bh][s][d], Kw[bh][s'][d] (s permuted per 32), Vt[bh][d][s]
    u16* Qw = (u16*)d_ws;
    u16* Kw = Qw + (size_t)NB * NH * SS * DH;
    u16* Vt = Kw + (size_t)NB * NH * SS * DH;

    qkv_kernel<<<64 * (SS / 128), 256, 0, stream>>>(
        x, Wq, bq, Wk, bk, Wv, bv, Qw, Kw, Vt);
    attn_kernel<<<64 * (SS / 256), 256, 0, stream>>>(Qw, Kw, Vt, (float*)d_out);
}